// Round 5
// baseline (280.067 us; speedup 1.0000x reference)
//
#include <hip/hip_runtime.h>

#define P_ 3136
#define NTOT 50176
#define EPSV 1e-5f

typedef __bf16 bf16x8 __attribute__((ext_vector_type(8)));
typedef float f32x4 __attribute__((ext_vector_type(4)));
typedef unsigned short u16x8 __attribute__((ext_vector_type(8)));
typedef unsigned short u16x4 __attribute__((ext_vector_type(4)));

__device__ __forceinline__ unsigned short f2bf(float f) {
    unsigned u = __builtin_bit_cast(unsigned, f);
    unsigned r = u + 0x7fffu + ((u >> 16) & 1u);
    return (unsigned short)(r >> 16);
}
__device__ __forceinline__ float bf2f(unsigned short h) {
    unsigned u = ((unsigned)h) << 16;
    return __builtin_bit_cast(float, u);
}
// tanh-approx GELU (max abs err ~1e-3; clamp avoids exp overflow NaN)
__device__ __forceinline__ float gelu_fast(float x) {
    float x2 = x * x;
    float u2 = x * (1.5957691216f + 0.0713548162f * x2);
    u2 = fminf(u2, 80.0f);
    float e = __expf(u2);
    return x * e * __builtin_amdgcn_rcpf(e + 1.0f);
}
__device__ __forceinline__ void gload16(const void* g, void* l) {
    __builtin_amdgcn_global_load_lds(
        (const __attribute__((address_space(1))) void*)g,
        (__attribute__((address_space(3))) void*)l, 16, 0, 0);
}
__device__ __forceinline__ bf16x8 ldlds(const char* p) {
    return __builtin_bit_cast(bf16x8, *(const u16x8*)p);
}

#define PH_PRE  __builtin_amdgcn_s_barrier(); \
                asm volatile("s_waitcnt lgkmcnt(0)" ::: "memory"); \
                __builtin_amdgcn_sched_barrier(0); \
                __builtin_amdgcn_s_setprio(1)
#define PH_POST __builtin_amdgcn_s_setprio(0); \
                __builtin_amdgcn_sched_barrier(0); \
                __builtin_amdgcn_s_barrier()
#define PH_POSTV4 __builtin_amdgcn_s_setprio(0); \
                asm volatile("s_waitcnt vmcnt(4)" ::: "memory"); \
                __builtin_amdgcn_sched_barrier(0); \
                __builtin_amdgcn_s_barrier()
#define PH_POSTV6 __builtin_amdgcn_s_setprio(0); \
                asm volatile("s_waitcnt vmcnt(6)" ::: "memory"); \
                __builtin_amdgcn_sched_barrier(0); \
                __builtin_amdgcn_s_barrier()

// ---------------- prep: weights fp32 -> bf16 ----------------
__global__ __launch_bounds__(256)
void prep_w(const float* __restrict__ w1, const float* __restrict__ w2,
            const float* __restrict__ w3,
            unsigned short* __restrict__ o1, unsigned short* __restrict__ o2,
            unsigned short* __restrict__ o3)
{
    int i = blockIdx.x * 256 + threadIdx.x;
    const int n1 = 384 * 384 / 4, n2 = 768 * 768 / 4;
    const float* src; unsigned short* dst; int j;
    if (i < n1)           { src = w1; dst = o1; j = i; }
    else if (i < n1 + n2) { src = w2; dst = o2; j = i - n1; }
    else                  { src = w3; dst = o3; j = i - n1 - n2; }
    float4 f = *(const float4*)(src + (size_t)j * 4);
    u16x4 pk = { f2bf(f.x), f2bf(f.y), f2bf(f.z), f2bf(f.w) };
    *(u16x4*)(dst + (size_t)j * 4) = pk;
}

// ---------------- prep: BN scale/shift ----------------
__global__ __launch_bounds__(256)
void prep_bn(const float* b1, const float* g1, const float* be1, const float* m1, const float* v1,
             const float* b2, const float* g2, const float* be2, const float* m2, const float* v2,
             const float* b3, const float* g3, const float* be3, const float* m3, const float* v3,
             float* bn1, float* bn2, float* bn3)
{
    int i = blockIdx.x * 256 + threadIdx.x;
    const float *pb, *pg, *pbe, *pm, *pv; float* dst; int o, M;
    if (i < 384)       { pb=b1; pg=g1; pbe=be1; pm=m1; pv=v1; dst=bn1; o=i;        M=384; }
    else if (i < 1152) { pb=b2; pg=g2; pbe=be2; pm=m2; pv=v2; dst=bn2; o=i-384;    M=768; }
    else               { pb=b3; pg=g3; pbe=be3; pm=m3; pv=v3; dst=bn3; o=i-1152;   M=384; }
    float inv = pg[o] / sqrtf(pv[o] + EPSV);
    dst[o]     = inv;
    dst[M + o] = (pb[o] - pm[o]) * inv + pbe[o];
}

// ---------------- prep: x [b][c][p] fp32 -> xT [bp][c] bf16 ----------------
__global__ __launch_bounds__(256)
void prep_xT(const float* __restrict__ x, unsigned short* __restrict__ xT)
{
    __shared__ float tl[64][65];
    const int t = threadIdx.x;
    const int c0 = blockIdx.x * 64;
    const int p0 = blockIdx.y * 64;
    const int b  = blockIdx.z;
    const float* xb = x + ((size_t)b * 384 + c0) * P_ + p0;
    {
        int c = t >> 2, j0 = (t & 3) * 16;
        #pragma unroll
        for (int j = 0; j < 16; j += 4) {
            float4 f4 = *(const float4*)(xb + (size_t)c * P_ + j0 + j);
            tl[c][j0 + j]     = f4.x; tl[c][j0 + j + 1] = f4.y;
            tl[c][j0 + j + 2] = f4.z; tl[c][j0 + j + 3] = f4.w;
        }
    }
    __syncthreads();
    {
        int p = t >> 2, c1 = (t & 3) * 16;
        unsigned short buf[16];
        #pragma unroll
        for (int j = 0; j < 16; ++j) buf[j] = f2bf(tl[c1 + j][p]);
        unsigned short* dst = xT + ((size_t)b * P_ + p0 + p) * 384 + c0 + c1;
        *(u16x8*)dst       = *(u16x8*)buf;
        *(u16x8*)(dst + 8) = *(u16x8*)(buf + 8);
    }
}

// ============ GEMM2: 256x256x64 tile, 512 thr (8 waves 2Mx4N, wave tile 128x64) ============
// A = gc_w [768][768] bf16; B = In [NTOT][768] bf16. Out bf16 [col][768]+o0 with BN+gelu.
// LDS 160KB: A triple-buf @0/32K/64K (32KB each), B double-buf @96K/128K.
// Counted vmcnt(4) once per K-tile; B staged 1 tile ahead, A 2 tiles ahead.
// Each operand fragment ds_read exactly once per K-tile (24 b128/wave).
__global__ __launch_bounds__(512, 2)
void gemmG(const unsigned short* __restrict__ W,
           const unsigned short* __restrict__ In,
           unsigned short* __restrict__ Out,
           const float* __restrict__ bnp)
{
    constexpr int KD = 768;
    constexpr int NT = 12;
    __shared__ __align__(16) char lds[160 * 1024];

    const int t    = threadIdx.x;
    const int lane = t & 63;
    const int wave = t >> 6;
    const int wm = wave >> 2, wn = wave & 3;
    const int fr = lane & 15, fg = lane >> 4;

    // bijective XCD chunk swizzle, M-fastest (3 M-tiles share B panel on one XCD)
    const int nwg = gridDim.x;
    int id = blockIdx.x;
    int q = nwg >> 3, r = nwg & 7;
    int xcd = id & 7, pos = id >> 3;
    int wg = (xcd < r ? xcd * (q + 1) : r * (q + 1) + (xcd - r) * q) + pos;
    const int m0 = (wg % 3) * 256;
    const int n0 = (wg / 3) * 256;

    // ---- staging setup ----
    const int pcu  = (((t & 7) ^ ((t >> 3) & 7)) << 3); // swizzled source col (ushorts)
    const int srow = t >> 3;
    const int dstT = t * 16;
    const unsigned short* pA[4];
    const unsigned short* pB[4];
    #pragma unroll
    for (int i = 0; i < 4; ++i) {
        pA[i] = W  + (size_t)(m0 + i * 64 + srow) * KD + pcu;
        pB[i] = In + (size_t)(n0 + i * 64 + srow) * KD + pcu;
    }
    auto stA = [&](int kt) {  // 4 gloads -> A buf kt%3
        int kk = (kt < NT ? kt : NT - 1) * 64;
        char* base = lds + (kt % 3) * 32768 + dstT;
        #pragma unroll
        for (int i = 0; i < 4; ++i) gload16(pA[i] + kk, base + i * 8192);
    };
    auto stB = [&](int kt) {  // 4 gloads -> B buf kt&1
        int kk = (kt < NT ? kt : NT - 1) * 64;
        char* base = lds + 98304 + (kt & 1) * 32768 + dstT;
        #pragma unroll
        for (int i = 0; i < 4; ++i) gload16(pB[i] + kk, base + i * 8192);
    };

    // ---- fragment read setup ----
    const int ko0 = (fg * 16) ^ ((fr & 7) << 4);
    const int ko1 = (64 + fg * 16) ^ ((fr & 7) << 4);

    bf16x8 afr[4][2], bfr[4][2];
    f32x4 acc[8][4] = {};

    auto loadA = [&](int ab, int h) {
        const char* base = lds + ab * 32768 + (wm * 128 + h * 64 + fr) * 128;
        #pragma unroll
        for (int mf = 0; mf < 4; ++mf) {
            afr[mf][0] = ldlds(base + mf * 2048 + ko0);
            afr[mf][1] = ldlds(base + mf * 2048 + ko1);
        }
    };
    auto loadB = [&](int d) {
        const char* base = lds + 98304 + d * 32768 + (wn * 64 + fr) * 128;
        #pragma unroll
        for (int nf = 0; nf < 4; ++nf) {
            bfr[nf][0] = ldlds(base + nf * 2048 + ko0);
            bfr[nf][1] = ldlds(base + nf * 2048 + ko1);
        }
    };
    auto quad = [&](int h) {
        #pragma unroll
        for (int ks = 0; ks < 2; ++ks)
            #pragma unroll
            for (int mf = 0; mf < 4; ++mf)
                #pragma unroll
                for (int nf = 0; nf < 4; ++nf)
                    acc[h * 4 + mf][nf] = __builtin_amdgcn_mfma_f32_16x16x32_bf16(
                        afr[mf][ks], bfr[nf][ks], acc[h * 4 + mf][nf], 0, 0, 0);
    };

    // ---- prologue: A(0), B(0), A(1) ----
    stA(0); stB(0); stA(1);
    asm volatile("s_waitcnt vmcnt(4)" ::: "memory");
    __builtin_amdgcn_sched_barrier(0);
    __builtin_amdgcn_s_barrier();

    for (int kt = 0; kt < NT; ++kt) {
        const int ab = kt % 3, d = kt & 1;
        // ph0: read A-half0 + all B of tile kt; prefetch B(kt+1)
        loadA(ab, 0); loadB(d); stB(kt + 1);
        PH_PRE; quad(0); PH_POST;
        // ph1: read A-half1; prefetch A(kt+2)
        loadA(ab, 1); stA(kt + 2);
        PH_PRE; quad(1); PH_POSTV4;
    }

    // ---- epilogue: BN + gelu -> bf16 [col][768] ----
    #pragma unroll
    for (int mA = 0; mA < 8; ++mA) {
        const int o0 = m0 + wm * 128 + (mA >> 2) * 64 + (mA & 3) * 16 + fg * 4;
        f32x4 inv = *(const f32x4*)(bnp + o0);
        f32x4 sh  = *(const f32x4*)(bnp + 768 + o0);
        #pragma unroll
        for (int nf = 0; nf < 4; ++nf) {
            const int col = n0 + wn * 64 + nf * 16 + fr;
            u16x4 pk;
            #pragma unroll
            for (int rr = 0; rr < 4; ++rr)
                pk[rr] = f2bf(gelu_fast(acc[mA][nf][rr] * inv[rr] + sh[rr]));
            *(u16x4*)(Out + (size_t)col * 768 + o0) = pk;
        }
    }
    asm volatile("s_waitcnt vmcnt(0)" ::: "memory");
}

// ============ unified GEMM (G1/G3): BM=128, BN=256, BK=64, 512 thr (8 waves 2Mx4N) ============
template<int KDIM, int MDIM, int EPI>
__global__ __launch_bounds__(512, 1)
void gemmU(const unsigned short* __restrict__ W,
           const unsigned short* __restrict__ In,
           void* __restrict__ OutV,
           const float* __restrict__ bnp,
           const float* __restrict__ res)
{
    constexpr int NT = KDIM / 64;
    constexpr int MT = MDIM / 128;
    __shared__ __align__(16) char lds[106496];

    const int t    = threadIdx.x;
    const int lane = t & 63;
    const int wave = t >> 6;
    const int wm = wave >> 2, wn = wave & 3;
    const int fr = lane & 15, fg = lane >> 4;

    const int nwg = gridDim.x;
    int id = blockIdx.x;
    int q = nwg >> 3, r = nwg & 7;
    int xcd = id & 7, pos = id >> 3;
    int wg = (xcd < r ? xcd * (q + 1) : r * (q + 1) + (xcd - r) * q) + pos;
    const int m0 = (wg % MT) * 128;
    const int n0 = (wg / MT) * 256;

    const int pcu  = (((t & 7) ^ ((t >> 3) & 7)) << 3);
    const int srow = t >> 3;
    const int dstT = t * 16;
    const unsigned short* pA[2];
    const unsigned short* pB[4];
    #pragma unroll
    for (int i = 0; i < 2; ++i) pA[i] = W  + (size_t)(m0 + i * 64 + srow) * KDIM + pcu;
    #pragma unroll
    for (int j = 0; j < 4; ++j) pB[j] = In + (size_t)(n0 + j * 64 + srow) * KDIM + pcu;

    auto stA = [&](int kt) {
        int live = kt < NT;
        int kk = (live ? kt : NT - 1) * 64;
        int b0 = live ? (kt & 1) * 16384 + dstT        : 98304 + dstT;
        int b1 = live ? (kt & 1) * 16384 + 8192 + dstT : 98304 + dstT;
        gload16(pA[0] + kk, lds + b0);
        gload16(pA[1] + kk, lds + b1);
    };
    auto stB0 = [&](int kt) {
        int live = kt < NT;
        int kk = (live ? kt : NT - 1) * 64;
        int b0 = live ? 32768 + (kt & 1) * 32768 + dstT        : 98304 + dstT;
        int b1 = live ? 32768 + (kt & 1) * 32768 + 8192 + dstT : 98304 + dstT;
        gload16(pB[0] + kk, lds + b0);
        gload16(pB[1] + kk, lds + b1);
    };
    auto stB1 = [&](int kt) {
        int live = kt < NT;
        int kk = (live ? kt : NT - 1) * 64;
        int b0 = live ? 32768 + (kt & 1) * 32768 + 16384 + dstT : 98304 + dstT;
        int b1 = live ? 32768 + (kt & 1) * 32768 + 24576 + dstT : 98304 + dstT;
        gload16(pB[2] + kk, lds + b0);
        gload16(pB[3] + kk, lds + b1);
    };

    const int swz = (fr & 7) << 4;
    const int ko0 = (fg * 16) ^ swz;
    const int ko1 = (64 + fg * 16) ^ swz;
    const int arow = wm * 64 + fr;
    const int brow = wn * 32 + fr;

    bf16x8 afr[4][2], bfr[2][2];
    f32x4 acc[4][4] = {};

    auto loadA = [&](int d) {
        const char* base = lds + d * 16384 + arow * 128;
        #pragma unroll
        for (int mf = 0; mf < 4; ++mf) {
            afr[mf][0] = ldlds(base + mf * 2048 + ko0);
            afr[mf][1] = ldlds(base + mf * 2048 + ko1);
        }
    };
    auto loadB = [&](int d, int jsel) {
        const char* base = lds + 32768 + d * 32768 + (jsel * 128 + brow) * 128;
        #pragma unroll
        for (int nf = 0; nf < 2; ++nf) {
            bfr[nf][0] = ldlds(base + nf * 2048 + ko0);
            bfr[nf][1] = ldlds(base + nf * 2048 + ko1);
        }
    };
    auto quad = [&](int jsel) {
        #pragma unroll
        for (int ks = 0; ks < 2; ++ks)
            #pragma unroll
            for (int mf = 0; mf < 4; ++mf)
                #pragma unroll
                for (int nf = 0; nf < 2; ++nf)
                    acc[mf][jsel * 2 + nf] = __builtin_amdgcn_mfma_f32_16x16x32_bf16(
                        afr[mf][ks], bfr[nf][ks], acc[mf][jsel * 2 + nf], 0, 0, 0);
    };

    stA(0); stB0(0); stB1(0); stA(1); stB0(1);
    asm volatile("s_waitcnt vmcnt(6)" ::: "memory");
    __builtin_amdgcn_sched_barrier(0);
    __builtin_amdgcn_s_barrier();

    for (int it = 0; it < NT / 2; ++it) {
        const int kt = 2 * it;
        loadA(0); loadB(0, 0); stB1(kt + 1);
        PH_PRE; quad(0); PH_POSTV6;
        loadB(0, 1); stA(kt + 2); stB0(kt + 2);
        PH_PRE; quad(1); PH_POSTV6;
        loadA(1); loadB(1, 0); stB1(kt + 2);
        PH_PRE; quad(0); PH_POSTV6;
        loadB(1, 1); stA(kt + 3); stB0(kt + 3);
        PH_PRE; quad(1); PH_POSTV6;
    }

    #pragma unroll
    for (int mf = 0; mf < 4; ++mf) {
        const int o0 = m0 + wm * 64 + mf * 16 + fg * 4;
        f32x4 inv = *(const f32x4*)(bnp + o0);
        f32x4 sh  = *(const f32x4*)(bnp + MDIM + o0);
        if (EPI < 2) {
            unsigned short* Out = (unsigned short*)OutV;
            #pragma unroll
            for (int nB = 0; nB < 4; ++nB) {
                const int col = n0 + (nB >> 1) * 128 + wn * 32 + (nB & 1) * 16 + fr;
                u16x4 pk;
                #pragma unroll
                for (int rr = 0; rr < 4; ++rr) {
                    float v = acc[mf][nB][rr] * inv[rr] + sh[rr];
                    if (EPI == 1) v = gelu_fast(v);
                    pk[rr] = f2bf(v);
                }
                *(u16x4*)(Out + (size_t)col * 768 + o0) = pk;
            }
        } else {
            float* Out = (float*)OutV;
            #pragma unroll
            for (int nB = 0; nB < 4; ++nB) {
                const int col = n0 + (nB >> 1) * 128 + wn * 32 + (nB & 1) * 16 + fr;
                const int b = col / P_;
                const int p = col - b * P_;
                const size_t base = (size_t)b * 384 * P_ + p;
                #pragma unroll
                for (int rr = 0; rr < 4; ++rr) {
                    int o = o0 + rr;
                    Out[base + (size_t)o * P_] =
                        acc[mf][nB][rr] * inv[rr] + sh[rr] + res[base + (size_t)o * P_];
                }
            }
        }
    }
    asm volatile("s_waitcnt vmcnt(0)" ::: "memory");
}

// ---------------- mrconv pass 1: per-(b, w|h) parity mins ----------------
#define MINSEG (16 * 2 * 56 * 384)
__global__ __launch_bounds__(384)
void mr_min(const unsigned short* __restrict__ y, float* __restrict__ mins)
{
    const int c = threadIdx.x;
    const int q = blockIdx.x;
    const int b = blockIdx.y;
    const unsigned short* yb = y + (size_t)b * P_ * 768;
    float m1e = 3.4e38f, m2e = 3.4e38f, m1o = 3.4e38f, m2o = 3.4e38f;
    if (q < 56) {
        int w = q;
        for (int h = 0; h < 56; h += 2) {
            float v0 = bf2f(yb[(size_t)(h * 56 + w) * 768 + c]);
            float v1 = bf2f(yb[(size_t)((h + 1) * 56 + w) * 768 + c]);
            if (v0 < m1e) { m2e = m1e; m1e = v0; } else if (v0 < m2e) m2e = v0;
            if (v1 < m1o) { m2o = m1o; m1o = v1; } else if (v1 < m2o) m2o = v1;
        }
        float* cm1 = mins;
        float* cm2 = mins + MINSEG;
        cm1[((b * 2 + 0) * 56 + w) * 384 + c] = m1e;
        cm1[((b * 2 + 1) * 56 + w) * 384 + c] = m1o;
        cm2[((b * 2 + 0) * 56 + w) * 384 + c] = m2e;
        cm2[((b * 2 + 1) * 56 + w) * 384 + c] = m2o;
    } else {
        int h = q - 56;
        for (int w = 0; w < 56; w += 2) {
            float v0 = bf2f(yb[(size_t)(h * 56 + w) * 768 + c]);
            float v1 = bf2f(yb[(size_t)(h * 56 + w + 1) * 768 + c]);
            if (v0 < m1e) { m2e = m1e; m1e = v0; } else if (v0 < m2e) m2e = v0;
            if (v1 < m1o) { m2o = m1o; m1o = v1; } else if (v1 < m2o) m2o = v1;
        }
        float* rm1 = mins + 2 * MINSEG;
        float* rm2 = mins + 3 * MINSEG;
        rm1[((b * 2 + 0) * 56 + h) * 384 + c] = m1e;
        rm1[((b * 2 + 1) * 56 + h) * 384 + c] = m1o;
        rm2[((b * 2 + 0) * 56 + h) * 384 + c] = m2e;
        rm2[((b * 2 + 1) * 56 + h) * 384 + c] = m2o;
    }
}

// ---------------- mrconv pass 2: combine -> y[:, 384:768] ----------------
__global__ __launch_bounds__(384)
void mr_comb(unsigned short* __restrict__ y, const float* __restrict__ mins)
{
    const int c = threadIdx.x;
    const int h = blockIdx.x;
    const int b = blockIdx.y;
    unsigned short* yb = y + (size_t)b * P_ * 768;
    const float* cm1 = mins;
    const float* cm2 = mins + MINSEG;
    const float* rm1 = mins + 2 * MINSEG;
    const float* rm2 = mins + 3 * MINSEG;
    const int parh = h & 1;
    float r1e = rm1[((b * 2 + 0) * 56 + h) * 384 + c];
    float r2e = rm2[((b * 2 + 0) * 56 + h) * 384 + c];
    float r1o = rm1[((b * 2 + 1) * 56 + h) * 384 + c];
    float r2o = rm2[((b * 2 + 1) * 56 + h) * 384 + c];
    #pragma unroll 2
    for (int w = 0; w < 56; ++w) {
        float v  = bf2f(yb[(size_t)(h * 56 + w) * 768 + c]);
        float c1 = cm1[((b * 2 + parh) * 56 + w) * 384 + c];
        float c2 = cm2[((b * 2 + parh) * 56 + w) * 384 + c];
        float mh = v > c1 ? c1 : c2;
        float rw1 = (w & 1) ? r1o : r1e;
        float rw2 = (w & 1) ? r2o : r2e;
        float mw = v > rw1 ? rw1 : rw2;
        float xj = fmaxf(0.0f, v - fminf(mh, mw));
        yb[(size_t)(h * 56 + w) * 768 + 384 + c] = f2bf(xj);
    }
}

extern "C" void kernel_launch(void* const* d_in, const int* in_sizes, int n_in,
                              void* d_out, int out_size, void* d_ws, size_t ws_size,
                              hipStream_t stream)
{
    const float* x      = (const float*)d_in[0];
    const float* fc1_w  = (const float*)d_in[1];
    const float* fc1_b  = (const float*)d_in[2];
    const float* fc1_g  = (const float*)d_in[3];
    const float* fc1_be = (const float*)d_in[4];
    const float* fc1_m  = (const float*)d_in[5];
    const float* fc1_v  = (const float*)d_in[6];
    const float* gc_w   = (const float*)d_in[7];
    const float* gc_b   = (const float*)d_in[8];
    const float* gc_g   = (const float*)d_in[9];
    const float* gc_be  = (const float*)d_in[10];
    const float* gc_m   = (const float*)d_in[11];
    const float* gc_v   = (const float*)d_in[12];
    const float* fc2_w  = (const float*)d_in[13];
    const float* fc2_b  = (const float*)d_in[14];
    const float* fc2_g  = (const float*)d_in[15];
    const float* fc2_be = (const float*)d_in[16];
    const float* fc2_m  = (const float*)d_in[17];
    const float* fc2_v  = (const float*)d_in[18];

    char* ws = (char*)d_ws;
    unsigned short* y   = (unsigned short*)ws;                       // [NTOT][768] bf16
    unsigned short* g   = y + (size_t)NTOT * 768;                    // [NTOT][768] bf16
    unsigned short* xT  = g + (size_t)NTOT * 768;                    // [NTOT][384] bf16
    unsigned short* wb1 = xT + (size_t)NTOT * 384;                   // [384][384]
    unsigned short* wb2 = wb1 + 384 * 384;                           // [768][768]
    unsigned short* wb3 = wb2 + 768 * 768;                           // [384][768]
    float* bn1 = (float*)(wb3 + 384 * 768);                          // [2][384]
    float* bn2 = bn1 + 2 * 384;                                      // [2][768]
    float* bn3 = bn2 + 2 * 768;                                      // [2][384]
    float* mins = bn3 + 2 * 384;                                     // 4 * MINSEG

    prep_w<<<1008, 256, 0, stream>>>(fc1_w, gc_w, fc2_w, wb1, wb2, wb3);
    prep_bn<<<6, 256, 0, stream>>>(fc1_b, fc1_g, fc1_be, fc1_m, fc1_v,
                                   gc_b, gc_g, gc_be, gc_m, gc_v,
                                   fc2_b, fc2_g, fc2_be, fc2_m, fc2_v,
                                   bn1, bn2, bn3);
    prep_xT<<<dim3(6, 49, 16), 256, 0, stream>>>(x, xT);

    // y[:, 0:384] = bn(fc1 @ x)
    gemmU<384, 384, 0><<<dim3(3 * 196), 512, 0, stream>>>(wb1, xT, y, bn1, nullptr);
    // y[:, 384:768] = mrconv
    mr_min<<<dim3(112, 16), 384, 0, stream>>>(y, mins);
    mr_comb<<<dim3(56, 16), 384, 0, stream>>>(y, mins);
    // g = gelu(bn(gc @ y))  -- 256x256 big-tile kernel
    gemmG<<<dim3(3 * 196), 512, 0, stream>>>(wb2, y, g, bn2);
    // out = bn(fc2 @ g) + x
    gemmU<768, 384, 2><<<dim3(3 * 196), 512, 0, stream>>>(wb3, g, (void*)d_out, bn3, x);
}

// Round 6
// 247.869 us; speedup vs baseline: 1.1299x; 1.1299x over previous
//
#include <hip/hip_runtime.h>

#define P_ 3136
#define NTOT 50176
#define EPSV 1e-5f

typedef __bf16 bf16x8 __attribute__((ext_vector_type(8)));
typedef float f32x4 __attribute__((ext_vector_type(4)));
typedef unsigned short u16x8 __attribute__((ext_vector_type(8)));
typedef unsigned short u16x4 __attribute__((ext_vector_type(4)));

__device__ __forceinline__ unsigned short f2bf(float f) {
    unsigned u = __builtin_bit_cast(unsigned, f);
    unsigned r = u + 0x7fffu + ((u >> 16) & 1u);
    return (unsigned short)(r >> 16);
}
__device__ __forceinline__ float bf2f(unsigned short h) {
    unsigned u = ((unsigned)h) << 16;
    return __builtin_bit_cast(float, u);
}
// tanh-approx GELU (max abs err ~1e-3; clamp avoids exp overflow NaN)
__device__ __forceinline__ float gelu_fast(float x) {
    float x2 = x * x;
    float u2 = x * (1.5957691216f + 0.0713548162f * x2);
    u2 = fminf(u2, 80.0f);
    float e = __expf(u2);
    return x * e * __builtin_amdgcn_rcpf(e + 1.0f);
}
__device__ __forceinline__ void gload16(const void* g, void* l) {
    __builtin_amdgcn_global_load_lds(
        (const __attribute__((address_space(1))) void*)g,
        (__attribute__((address_space(3))) void*)l, 16, 0, 0);
}
__device__ __forceinline__ bf16x8 ldlds(const char* p) {
    return __builtin_bit_cast(bf16x8, *(const u16x8*)p);
}

#define PH_PRE  __builtin_amdgcn_s_barrier(); \
                asm volatile("s_waitcnt lgkmcnt(0)" ::: "memory"); \
                __builtin_amdgcn_sched_barrier(0); \
                __builtin_amdgcn_s_setprio(1)
#define PH_POSTV6 __builtin_amdgcn_s_setprio(0); \
                asm volatile("s_waitcnt vmcnt(6)" ::: "memory"); \
                __builtin_amdgcn_sched_barrier(0); \
                __builtin_amdgcn_s_barrier()

// ---------------- prep: weights fp32 -> bf16 ----------------
__global__ __launch_bounds__(256)
void prep_w(const float* __restrict__ w1, const float* __restrict__ w2,
            const float* __restrict__ w3,
            unsigned short* __restrict__ o1, unsigned short* __restrict__ o2,
            unsigned short* __restrict__ o3)
{
    int i = blockIdx.x * 256 + threadIdx.x;
    const int n1 = 384 * 384 / 4, n2 = 768 * 768 / 4;
    const float* src; unsigned short* dst; int j;
    if (i < n1)           { src = w1; dst = o1; j = i; }
    else if (i < n1 + n2) { src = w2; dst = o2; j = i - n1; }
    else                  { src = w3; dst = o3; j = i - n1 - n2; }
    float4 f = *(const float4*)(src + (size_t)j * 4);
    u16x4 pk = { f2bf(f.x), f2bf(f.y), f2bf(f.z), f2bf(f.w) };
    *(u16x4*)(dst + (size_t)j * 4) = pk;
}

// ---------------- prep: BN scale/shift ----------------
__global__ __launch_bounds__(256)
void prep_bn(const float* b1, const float* g1, const float* be1, const float* m1, const float* v1,
             const float* b2, const float* g2, const float* be2, const float* m2, const float* v2,
             const float* b3, const float* g3, const float* be3, const float* m3, const float* v3,
             float* bn1, float* bn2, float* bn3)
{
    int i = blockIdx.x * 256 + threadIdx.x;
    const float *pb, *pg, *pbe, *pm, *pv; float* dst; int o, M;
    if (i < 384)       { pb=b1; pg=g1; pbe=be1; pm=m1; pv=v1; dst=bn1; o=i;        M=384; }
    else if (i < 1152) { pb=b2; pg=g2; pbe=be2; pm=m2; pv=v2; dst=bn2; o=i-384;    M=768; }
    else               { pb=b3; pg=g3; pbe=be3; pm=m3; pv=v3; dst=bn3; o=i-1152;   M=384; }
    float inv = pg[o] / sqrtf(pv[o] + EPSV);
    dst[o]     = inv;
    dst[M + o] = (pb[o] - pm[o]) * inv + pbe[o];
}

// ---------------- prep: x [b][c][p] fp32 -> xT [bp][c] bf16 ----------------
__global__ __launch_bounds__(256)
void prep_xT(const float* __restrict__ x, unsigned short* __restrict__ xT)
{
    __shared__ float tl[64][65];
    const int t = threadIdx.x;
    const int c0 = blockIdx.x * 64;
    const int p0 = blockIdx.y * 64;
    const int b  = blockIdx.z;
    const float* xb = x + ((size_t)b * 384 + c0) * P_ + p0;
    {
        int c = t >> 2, j0 = (t & 3) * 16;
        #pragma unroll
        for (int j = 0; j < 16; j += 4) {
            float4 f4 = *(const float4*)(xb + (size_t)c * P_ + j0 + j);
            tl[c][j0 + j]     = f4.x; tl[c][j0 + j + 1] = f4.y;
            tl[c][j0 + j + 2] = f4.z; tl[c][j0 + j + 3] = f4.w;
        }
    }
    __syncthreads();
    {
        int p = t >> 2, c1 = (t & 3) * 16;
        unsigned short buf[16];
        #pragma unroll
        for (int j = 0; j < 16; ++j) buf[j] = f2bf(tl[c1 + j][p]);
        unsigned short* dst = xT + ((size_t)b * P_ + p0 + p) * 384 + c0 + c1;
        *(u16x8*)dst       = *(u16x8*)buf;
        *(u16x8*)(dst + 8) = *(u16x8*)(buf + 8);
    }
}

// ============ fine GEMM (G2/G3): 128x128x64, 256 thr (4 waves 2x2, wave 64x64) ============
// K = 768 fixed. A = W [MDIM][768], B = In [NTOT][768], both bf16 k-contig rows.
// LDS 64KB: buf d at d*32768 {A 16KB, B 16KB}; double-buffered, 2 blocks/CU.
// Counted loop: stage(kt+1) issued first, vmcnt(8) -> tile kt ready; never drains to 0.
// EPI 1: BN+gelu -> bf16 [col][768], LDS-transposed coalesced u16x8 stores.
// EPI 2: BN+residual -> fp32 [b][o][p], LDS-transposed coalesced dword IO.
template<int MDIM, int EPI>
__global__ __launch_bounds__(256, 2)
void gemmF(const unsigned short* __restrict__ W,
           const unsigned short* __restrict__ In,
           void* __restrict__ OutV,
           const float* __restrict__ bnp,
           const float* __restrict__ res)
{
    constexpr int KD = 768;
    constexpr int NT = 12;
    constexpr int MT = MDIM / 128;
    __shared__ __align__(16) char lds[65536];

    const int t    = threadIdx.x;
    const int lane = t & 63;
    const int wave = t >> 6;
    const int wm = wave >> 1, wn = wave & 1;
    const int fr = lane & 15, fg = lane >> 4;

    // bijective XCD chunk swizzle, M-fastest (MT consecutive wg share a B panel)
    const int nwg = gridDim.x;
    int id = blockIdx.x;
    int q = nwg >> 3, r = nwg & 7;
    int xcd = id & 7, pos = id >> 3;
    int wg = (xcd < r ? xcd * (q + 1) : r * (q + 1) + (xcd - r) * q) + pos;
    const int m0 = (wg % MT) * 128;
    const int n0 = (wg / MT) * 128;

    // ---- staging setup: 32KB/K-tile = 8 gloads of 4KB ----
    const int pcu  = (((t & 7) ^ ((t >> 3) & 7)) << 3); // swizzled source col (ushorts)
    const int srow = t >> 3;                             // 0..31
    const unsigned short* pA[4];
    const unsigned short* pB[4];
    #pragma unroll
    for (int i = 0; i < 4; ++i) {
        pA[i] = W  + (size_t)(m0 + i * 32 + srow) * KD + pcu;
        pB[i] = In + (size_t)(n0 + i * 32 + srow) * KD + pcu;
    }
    auto stage = [&](int kt) {
        int kk = (kt < NT ? kt : NT - 1) * 64;
        char* base = lds + (kt & 1) * 32768 + t * 16;
        #pragma unroll
        for (int i = 0; i < 4; ++i) gload16(pA[i] + kk, base + i * 4096);
        #pragma unroll
        for (int i = 0; i < 4; ++i) gload16(pB[i] + kk, base + 16384 + i * 4096);
    };

    const int ko0 = (fg * 16) ^ ((fr & 7) << 4);
    const int ko1 = (64 + fg * 16) ^ ((fr & 7) << 4);
    const int arow = wm * 64 + fr;
    const int brow = wn * 64 + fr;

    bf16x8 afr[4][2], bfr[4][2];
    f32x4 acc[4][4] = {};

    stage(0);

    for (int kt = 0; kt < NT; ++kt) {
        stage(kt + 1);
        asm volatile("s_waitcnt vmcnt(8)" ::: "memory"); // tile kt fully in LDS
        __builtin_amdgcn_sched_barrier(0);
        __builtin_amdgcn_s_barrier();

        const char* base = lds + (kt & 1) * 32768;
        #pragma unroll
        for (int mf = 0; mf < 4; ++mf) {
            afr[mf][0] = ldlds(base + (arow + mf * 16) * 128 + ko0);
            afr[mf][1] = ldlds(base + (arow + mf * 16) * 128 + ko1);
        }
        #pragma unroll
        for (int nf = 0; nf < 4; ++nf) {
            bfr[nf][0] = ldlds(base + 16384 + (brow + nf * 16) * 128 + ko0);
            bfr[nf][1] = ldlds(base + 16384 + (brow + nf * 16) * 128 + ko1);
        }
        asm volatile("s_waitcnt lgkmcnt(0)" ::: "memory");
        __builtin_amdgcn_sched_barrier(0);
        __builtin_amdgcn_s_setprio(1);
        #pragma unroll
        for (int ks = 0; ks < 2; ++ks)
            #pragma unroll
            for (int mf = 0; mf < 4; ++mf)
                #pragma unroll
                for (int nf = 0; nf < 4; ++nf)
                    acc[mf][nf] = __builtin_amdgcn_mfma_f32_16x16x32_bf16(
                        afr[mf][ks], bfr[nf][ks], acc[mf][nf], 0, 0, 0);
        __builtin_amdgcn_s_setprio(0);
        __builtin_amdgcn_sched_barrier(0);
        __builtin_amdgcn_s_barrier(); // all waves done reading buf kt -> may be overwritten
    }

    // drain DMA + sync before overlaying LDS for the epilogue
    asm volatile("s_waitcnt vmcnt(0)" ::: "memory");
    __builtin_amdgcn_s_barrier();

    if (EPI == 1) {
        // [128 col][136 o-slot] u16 staging (row stride 272B = 17*16 -> 16B aligned)
        unsigned short* eL = (unsigned short*)lds;
        unsigned short* Out = (unsigned short*)OutV;
        #pragma unroll
        for (int mf = 0; mf < 4; ++mf) {
            const int o_l = wm * 64 + mf * 16 + fg * 4;
            f32x4 inv = *(const f32x4*)(bnp + m0 + o_l);
            f32x4 sh  = *(const f32x4*)(bnp + MDIM + m0 + o_l);
            #pragma unroll
            for (int nf = 0; nf < 4; ++nf) {
                const int col_l = wn * 64 + nf * 16 + fr;
                u16x4 pk;
                #pragma unroll
                for (int rr = 0; rr < 4; ++rr)
                    pk[rr] = f2bf(gelu_fast(acc[mf][nf][rr] * inv[rr] + sh[rr]));
                *(u16x4*)(eL + col_l * 136 + o_l) = pk;
            }
        }
        __builtin_amdgcn_s_barrier();
        #pragma unroll
        for (int i = 0; i < 8; ++i) {
            const int col_l = (t >> 4) + i * 16;
            const int o8 = (t & 15) * 8;
            u16x8 v = *(const u16x8*)(eL + col_l * 136 + o8);
            *(u16x8*)(Out + (size_t)(n0 + col_l) * 768 + m0 + o8) = v;
        }
    } else {
        // two halves of [64 o][132 col] fp32 staging; coalesced dword IO
        float* eL = (float*)lds;
        float* Out = (float*)OutV;
        #pragma unroll
        for (int h = 0; h < 2; ++h) {
            if (wm == h) {
                #pragma unroll
                for (int mf = 0; mf < 4; ++mf) {
                    const int o_l = mf * 16 + fg * 4;
                    f32x4 inv = *(const f32x4*)(bnp + m0 + h * 64 + o_l);
                    f32x4 sh  = *(const f32x4*)(bnp + MDIM + m0 + h * 64 + o_l);
                    #pragma unroll
                    for (int nf = 0; nf < 4; ++nf) {
                        const int col_l = wn * 64 + nf * 16 + fr;
                        #pragma unroll
                        for (int rr = 0; rr < 4; ++rr)
                            eL[(o_l + rr) * 132 + col_l] =
                                acc[mf][nf][rr] * inv[rr] + sh[rr];
                    }
                }
            }
            __builtin_amdgcn_s_barrier();
            #pragma unroll
            for (int i = 0; i < 32; ++i) {
                const int idx = i * 256 + t;
                const int o_i = idx >> 7, col = idx & 127;
                const int col_g = n0 + col;
                const int b = col_g / P_;
                const int p = col_g - b * P_;
                const size_t adr = (size_t)b * 384 * P_ + (size_t)(m0 + h * 64 + o_i) * P_ + p;
                Out[adr] = eL[o_i * 132 + col] + res[adr];
            }
            __builtin_amdgcn_s_barrier();
        }
    }
}

// ============ unified GEMM (G1): BM=128, BN=256, BK=64, 512 thr (8 waves 2Mx4N) ============
template<int KDIM, int MDIM, int EPI>
__global__ __launch_bounds__(512, 1)
void gemmU(const unsigned short* __restrict__ W,
           const unsigned short* __restrict__ In,
           void* __restrict__ OutV,
           const float* __restrict__ bnp,
           const float* __restrict__ res)
{
    constexpr int NT = KDIM / 64;
    constexpr int MT = MDIM / 128;
    __shared__ __align__(16) char lds[106496];

    const int t    = threadIdx.x;
    const int lane = t & 63;
    const int wave = t >> 6;
    const int wm = wave >> 2, wn = wave & 3;
    const int fr = lane & 15, fg = lane >> 4;

    const int nwg = gridDim.x;
    int id = blockIdx.x;
    int q = nwg >> 3, r = nwg & 7;
    int xcd = id & 7, pos = id >> 3;
    int wg = (xcd < r ? xcd * (q + 1) : r * (q + 1) + (xcd - r) * q) + pos;
    const int m0 = (wg % MT) * 128;
    const int n0 = (wg / MT) * 256;

    const int pcu  = (((t & 7) ^ ((t >> 3) & 7)) << 3);
    const int srow = t >> 3;
    const int dstT = t * 16;
    const unsigned short* pA[2];
    const unsigned short* pB[4];
    #pragma unroll
    for (int i = 0; i < 2; ++i) pA[i] = W  + (size_t)(m0 + i * 64 + srow) * KDIM + pcu;
    #pragma unroll
    for (int j = 0; j < 4; ++j) pB[j] = In + (size_t)(n0 + j * 64 + srow) * KDIM + pcu;

    auto stA = [&](int kt) {
        int live = kt < NT;
        int kk = (live ? kt : NT - 1) * 64;
        int b0 = live ? (kt & 1) * 16384 + dstT        : 98304 + dstT;
        int b1 = live ? (kt & 1) * 16384 + 8192 + dstT : 98304 + dstT;
        gload16(pA[0] + kk, lds + b0);
        gload16(pA[1] + kk, lds + b1);
    };
    auto stB0 = [&](int kt) {
        int live = kt < NT;
        int kk = (live ? kt : NT - 1) * 64;
        int b0 = live ? 32768 + (kt & 1) * 32768 + dstT        : 98304 + dstT;
        int b1 = live ? 32768 + (kt & 1) * 32768 + 8192 + dstT : 98304 + dstT;
        gload16(pB[0] + kk, lds + b0);
        gload16(pB[1] + kk, lds + b1);
    };
    auto stB1 = [&](int kt) {
        int live = kt < NT;
        int kk = (live ? kt : NT - 1) * 64;
        int b0 = live ? 32768 + (kt & 1) * 32768 + 16384 + dstT : 98304 + dstT;
        int b1 = live ? 32768 + (kt & 1) * 32768 + 24576 + dstT : 98304 + dstT;
        gload16(pB[2] + kk, lds + b0);
        gload16(pB[3] + kk, lds + b1);
    };

    const int swz = (fr & 7) << 4;
    const int ko0 = (fg * 16) ^ swz;
    const int ko1 = (64 + fg * 16) ^ swz;
    const int arow = wm * 64 + fr;
    const int brow = wn * 32 + fr;

    bf16x8 afr[4][2], bfr[2][2];
    f32x4 acc[4][4] = {};

    auto loadA = [&](int d) {
        const char* base = lds + d * 16384 + arow * 128;
        #pragma unroll
        for (int mf = 0; mf < 4; ++mf) {
            afr[mf][0] = ldlds(base + mf * 2048 + ko0);
            afr[mf][1] = ldlds(base + mf * 2048 + ko1);
        }
    };
    auto loadB = [&](int d, int jsel) {
        const char* base = lds + 32768 + d * 32768 + (jsel * 128 + brow) * 128;
        #pragma unroll
        for (int nf = 0; nf < 2; ++nf) {
            bfr[nf][0] = ldlds(base + nf * 2048 + ko0);
            bfr[nf][1] = ldlds(base + nf * 2048 + ko1);
        }
    };
    auto quad = [&](int jsel) {
        #pragma unroll
        for (int ks = 0; ks < 2; ++ks)
            #pragma unroll
            for (int mf = 0; mf < 4; ++mf)
                #pragma unroll
                for (int nf = 0; nf < 2; ++nf)
                    acc[mf][jsel * 2 + nf] = __builtin_amdgcn_mfma_f32_16x16x32_bf16(
                        afr[mf][ks], bfr[nf][ks], acc[mf][jsel * 2 + nf], 0, 0, 0);
    };

    stA(0); stB0(0); stB1(0); stA(1); stB0(1);
    asm volatile("s_waitcnt vmcnt(6)" ::: "memory");
    __builtin_amdgcn_sched_barrier(0);
    __builtin_amdgcn_s_barrier();

    for (int it = 0; it < NT / 2; ++it) {
        const int kt = 2 * it;
        loadA(0); loadB(0, 0); stB1(kt + 1);
        PH_PRE; quad(0); PH_POSTV6;
        loadB(0, 1); stA(kt + 2); stB0(kt + 2);
        PH_PRE; quad(1); PH_POSTV6;
        loadA(1); loadB(1, 0); stB1(kt + 2);
        PH_PRE; quad(0); PH_POSTV6;
        loadB(1, 1); stA(kt + 3); stB0(kt + 3);
        PH_PRE; quad(1); PH_POSTV6;
    }

    #pragma unroll
    for (int mf = 0; mf < 4; ++mf) {
        const int o0 = m0 + wm * 64 + mf * 16 + fg * 4;
        f32x4 inv = *(const f32x4*)(bnp + o0);
        f32x4 sh  = *(const f32x4*)(bnp + MDIM + o0);
        unsigned short* Out = (unsigned short*)OutV;
        #pragma unroll
        for (int nB = 0; nB < 4; ++nB) {
            const int col = n0 + (nB >> 1) * 128 + wn * 32 + (nB & 1) * 16 + fr;
            u16x4 pk;
            #pragma unroll
            for (int rr = 0; rr < 4; ++rr) {
                float v = acc[mf][nB][rr] * inv[rr] + sh[rr];
                if (EPI == 1) v = gelu_fast(v);
                pk[rr] = f2bf(v);
            }
            *(u16x4*)(Out + (size_t)col * 768 + o0) = pk;
        }
    }
    asm volatile("s_waitcnt vmcnt(0)" ::: "memory");
}

// ---------------- mrconv pass 1: per-(b, w|h) parity mins ----------------
#define MINSEG (16 * 2 * 56 * 384)
__global__ __launch_bounds__(384)
void mr_min(const unsigned short* __restrict__ y, float* __restrict__ mins)
{
    const int c = threadIdx.x;
    const int q = blockIdx.x;
    const int b = blockIdx.y;
    const unsigned short* yb = y + (size_t)b * P_ * 768;
    float m1e = 3.4e38f, m2e = 3.4e38f, m1o = 3.4e38f, m2o = 3.4e38f;
    if (q < 56) {
        int w = q;
        for (int h = 0; h < 56; h += 2) {
            float v0 = bf2f(yb[(size_t)(h * 56 + w) * 768 + c]);
            float v1 = bf2f(yb[(size_t)((h + 1) * 56 + w) * 768 + c]);
            if (v0 < m1e) { m2e = m1e; m1e = v0; } else if (v0 < m2e) m2e = v0;
            if (v1 < m1o) { m2o = m1o; m1o = v1; } else if (v1 < m2o) m2o = v1;
        }
        float* cm1 = mins;
        float* cm2 = mins + MINSEG;
        cm1[((b * 2 + 0) * 56 + w) * 384 + c] = m1e;
        cm1[((b * 2 + 1) * 56 + w) * 384 + c] = m1o;
        cm2[((b * 2 + 0) * 56 + w) * 384 + c] = m2e;
        cm2[((b * 2 + 1) * 56 + w) * 384 + c] = m2o;
    } else {
        int h = q - 56;
        for (int w = 0; w < 56; w += 2) {
            float v0 = bf2f(yb[(size_t)(h * 56 + w) * 768 + c]);
            float v1 = bf2f(yb[(size_t)(h * 56 + w + 1) * 768 + c]);
            if (v0 < m1e) { m2e = m1e; m1e = v0; } else if (v0 < m2e) m2e = v0;
            if (v1 < m1o) { m2o = m1o; m1o = v1; } else if (v1 < m2o) m2o = v1;
        }
        float* rm1 = mins + 2 * MINSEG;
        float* rm2 = mins + 3 * MINSEG;
        rm1[((b * 2 + 0) * 56 + h) * 384 + c] = m1e;
        rm1[((b * 2 + 1) * 56 + h) * 384 + c] = m1o;
        rm2[((b * 2 + 0) * 56 + h) * 384 + c] = m2e;
        rm2[((b * 2 + 1) * 56 + h) * 384 + c] = m2o;
    }
}

// ---------------- mrconv pass 2: combine -> y[:, 384:768] ----------------
__global__ __launch_bounds__(384)
void mr_comb(unsigned short* __restrict__ y, const float* __restrict__ mins)
{
    const int c = threadIdx.x;
    const int h = blockIdx.x;
    const int b = blockIdx.y;
    unsigned short* yb = y + (size_t)b * P_ * 768;
    const float* cm1 = mins;
    const float* cm2 = mins + MINSEG;
    const float* rm1 = mins + 2 * MINSEG;
    const float* rm2 = mins + 3 * MINSEG;
    const int parh = h & 1;
    float r1e = rm1[((b * 2 + 0) * 56 + h) * 384 + c];
    float r2e = rm2[((b * 2 + 0) * 56 + h) * 384 + c];
    float r1o = rm1[((b * 2 + 1) * 56 + h) * 384 + c];
    float r2o = rm2[((b * 2 + 1) * 56 + h) * 384 + c];
    #pragma unroll 2
    for (int w = 0; w < 56; ++w) {
        float v  = bf2f(yb[(size_t)(h * 56 + w) * 768 + c]);
        float c1 = cm1[((b * 2 + parh) * 56 + w) * 384 + c];
        float c2 = cm2[((b * 2 + parh) * 56 + w) * 384 + c];
        float mh = v > c1 ? c1 : c2;
        float rw1 = (w & 1) ? r1o : r1e;
        float rw2 = (w & 1) ? r2o : r2e;
        float mw = v > rw1 ? rw1 : rw2;
        float xj = fmaxf(0.0f, v - fminf(mh, mw));
        yb[(size_t)(h * 56 + w) * 768 + 384 + c] = f2bf(xj);
    }
}

extern "C" void kernel_launch(void* const* d_in, const int* in_sizes, int n_in,
                              void* d_out, int out_size, void* d_ws, size_t ws_size,
                              hipStream_t stream)
{
    const float* x      = (const float*)d_in[0];
    const float* fc1_w  = (const float*)d_in[1];
    const float* fc1_b  = (const float*)d_in[2];
    const float* fc1_g  = (const float*)d_in[3];
    const float* fc1_be = (const float*)d_in[4];
    const float* fc1_m  = (const float*)d_in[5];
    const float* fc1_v  = (const float*)d_in[6];
    const float* gc_w   = (const float*)d_in[7];
    const float* gc_b   = (const float*)d_in[8];
    const float* gc_g   = (const float*)d_in[9];
    const float* gc_be  = (const float*)d_in[10];
    const float* gc_m   = (const float*)d_in[11];
    const float* gc_v   = (const float*)d_in[12];
    const float* fc2_w  = (const float*)d_in[13];
    const float* fc2_b  = (const float*)d_in[14];
    const float* fc2_g  = (const float*)d_in[15];
    const float* fc2_be = (const float*)d_in[16];
    const float* fc2_m  = (const float*)d_in[17];
    const float* fc2_v  = (const float*)d_in[18];

    char* ws = (char*)d_ws;
    unsigned short* y   = (unsigned short*)ws;                       // [NTOT][768] bf16
    unsigned short* g   = y + (size_t)NTOT * 768;                    // [NTOT][768] bf16
    unsigned short* xT  = g + (size_t)NTOT * 768;                    // [NTOT][384] bf16
    unsigned short* wb1 = xT + (size_t)NTOT * 384;                   // [384][384]
    unsigned short* wb2 = wb1 + 384 * 384;                           // [768][768]
    unsigned short* wb3 = wb2 + 768 * 768;                           // [384][768]
    float* bn1 = (float*)(wb3 + 384 * 768);                          // [2][384]
    float* bn2 = bn1 + 2 * 384;                                      // [2][768]
    float* bn3 = bn2 + 2 * 768;                                      // [2][384]
    float* mins = bn3 + 2 * 384;                                     // 4 * MINSEG

    prep_w<<<1008, 256, 0, stream>>>(fc1_w, gc_w, fc2_w, wb1, wb2, wb3);
    prep_bn<<<6, 256, 0, stream>>>(fc1_b, fc1_g, fc1_be, fc1_m, fc1_v,
                                   gc_b, gc_g, gc_be, gc_m, gc_v,
                                   fc2_b, fc2_g, fc2_be, fc2_m, fc2_v,
                                   bn1, bn2, bn3);
    prep_xT<<<dim3(6, 49, 16), 256, 0, stream>>>(x, xT);

    // y[:, 0:384] = bn(fc1 @ x)
    gemmU<384, 384, 0><<<dim3(3 * 196), 512, 0, stream>>>(wb1, xT, y, bn1, nullptr);
    // y[:, 384:768] = mrconv
    mr_min<<<dim3(112, 16), 384, 0, stream>>>(y, mins);
    mr_comb<<<dim3(56, 16), 384, 0, stream>>>(y, mins);
    // g = gelu(bn(gc @ y))  -- fine 128x128 kernel, 2 blocks/CU
    gemmF<768, 1><<<dim3(6 * 392), 256, 0, stream>>>(wb2, y, g, bn2, nullptr);
    // out = bn(fc2 @ g) + x -- fine 128x128 kernel, coalesced fp32 epilogue
    gemmF<384, 2><<<dim3(3 * 392), 256, 0, stream>>>(wb3, g, (void*)d_out, bn3, x);
}

// Round 7
// 239.930 us; speedup vs baseline: 1.1673x; 1.0331x over previous
//
#include <hip/hip_runtime.h>

#define P_ 3136
#define NTOT 50176
#define EPSV 1e-5f

typedef __bf16 bf16x8 __attribute__((ext_vector_type(8)));
typedef float f32x4 __attribute__((ext_vector_type(4)));
typedef unsigned short u16x8 __attribute__((ext_vector_type(8)));
typedef unsigned short u16x4 __attribute__((ext_vector_type(4)));

__device__ __forceinline__ unsigned short f2bf(float f) {
    unsigned u = __builtin_bit_cast(unsigned, f);
    unsigned r = u + 0x7fffu + ((u >> 16) & 1u);
    return (unsigned short)(r >> 16);
}
__device__ __forceinline__ float bf2f(unsigned short h) {
    unsigned u = ((unsigned)h) << 16;
    return __builtin_bit_cast(float, u);
}
// tanh-approx GELU (max abs err ~1e-3; clamp avoids exp overflow NaN)
__device__ __forceinline__ float gelu_fast(float x) {
    float x2 = x * x;
    float u2 = x * (1.5957691216f + 0.0713548162f * x2);
    u2 = fminf(u2, 80.0f);
    float e = __expf(u2);
    return x * e * __builtin_amdgcn_rcpf(e + 1.0f);
}
__device__ __forceinline__ void gload16(const void* g, void* l) {
    __builtin_amdgcn_global_load_lds(
        (const __attribute__((address_space(1))) void*)g,
        (__attribute__((address_space(3))) void*)l, 16, 0, 0);
}
__device__ __forceinline__ bf16x8 ldlds(const char* p) {
    return __builtin_bit_cast(bf16x8, *(const u16x8*)p);
}

// ---------------- prep: weights fp32 -> bf16, + BN scale/shift ----------------
__global__ __launch_bounds__(256)
void prep_wb(const float* __restrict__ w1, const float* __restrict__ w2,
             const float* __restrict__ w3,
             unsigned short* __restrict__ o1, unsigned short* __restrict__ o2,
             unsigned short* __restrict__ o3,
             const float* b1, const float* g1, const float* be1, const float* m1, const float* v1,
             const float* b2, const float* g2, const float* be2, const float* m2, const float* v2,
             const float* b3, const float* g3, const float* be3, const float* m3, const float* v3,
             float* bn1, float* bn2, float* bn3)
{
    int i = blockIdx.x * 256 + threadIdx.x;
    const int n1 = 384 * 384 / 4, n2 = 768 * 768 / 4, n3 = 384 * 768 / 4;
    if (i < n1 + n2 + n3) {
        const float* src; unsigned short* dst; int j;
        if (i < n1)           { src = w1; dst = o1; j = i; }
        else if (i < n1 + n2) { src = w2; dst = o2; j = i - n1; }
        else                  { src = w3; dst = o3; j = i - n1 - n2; }
        float4 f = *(const float4*)(src + (size_t)j * 4);
        u16x4 pk = { f2bf(f.x), f2bf(f.y), f2bf(f.z), f2bf(f.w) };
        *(u16x4*)(dst + (size_t)j * 4) = pk;
    } else {
        int k = i - (n1 + n2 + n3);  // 0..1535
        const float *pb, *pg, *pbe, *pm, *pv; float* dst; int o, M;
        if (k < 384)       { pb=b1; pg=g1; pbe=be1; pm=m1; pv=v1; dst=bn1; o=k;        M=384; }
        else if (k < 1152) { pb=b2; pg=g2; pbe=be2; pm=m2; pv=v2; dst=bn2; o=k-384;    M=768; }
        else               { pb=b3; pg=g3; pbe=be3; pm=m3; pv=v3; dst=bn3; o=k-1152;   M=384; }
        float inv = pg[o] / sqrtf(pv[o] + EPSV);
        dst[o]     = inv;
        dst[M + o] = (pb[o] - pm[o]) * inv + pbe[o];
    }
}

// ---------------- prep: x [b][c][p] fp32 -> xT [bp][c] bf16 ----------------
__global__ __launch_bounds__(256)
void prep_xT(const float* __restrict__ x, unsigned short* __restrict__ xT)
{
    __shared__ float tl[64][65];
    const int t = threadIdx.x;
    const int c0 = blockIdx.x * 64;
    const int p0 = blockIdx.y * 64;
    const int b  = blockIdx.z;
    const float* xb = x + ((size_t)b * 384 + c0) * P_ + p0;
    {
        int c = t >> 2, j0 = (t & 3) * 16;
        #pragma unroll
        for (int j = 0; j < 16; j += 4) {
            float4 f4 = *(const float4*)(xb + (size_t)c * P_ + j0 + j);
            tl[c][j0 + j]     = f4.x; tl[c][j0 + j + 1] = f4.y;
            tl[c][j0 + j + 2] = f4.z; tl[c][j0 + j + 3] = f4.w;
        }
    }
    __syncthreads();
    {
        int p = t >> 2, c1 = (t & 3) * 16;
        unsigned short buf[16];
        #pragma unroll
        for (int j = 0; j < 16; ++j) buf[j] = f2bf(tl[c1 + j][p]);
        unsigned short* dst = xT + ((size_t)b * P_ + p0 + p) * 384 + c0 + c1;
        *(u16x8*)dst       = *(u16x8*)buf;
        *(u16x8*)(dst + 8) = *(u16x8*)(buf + 8);
    }
}

// ============ fine GEMM (all three): 128x128x64, 256 thr (4 waves 2x2, wave 64x64) ============
// A = W [MDIM][KD], B = In [NTOT][KD], both bf16 k-contig rows.
// LDS 64KB: buf d at d*32768 {A 16KB, B 16KB}; double-buffered, 2 blocks/CU.
// Counted loop: stage(kt+1) first, vmcnt(8) -> tile kt ready. Compiler-scheduled
// ds_read/MFMA interleave (plain loads, counted lgkmcnt by compiler; no manual pins).
// EPI 0: BN -> bf16 [col][768]+o0.  EPI 1: +gelu.  EPI 2: BN+res -> fp32 [b][o][p].
template<int KD, int MDIM, int EPI>
__global__ __launch_bounds__(256, 2)
void gemmF(const unsigned short* __restrict__ W,
           const unsigned short* __restrict__ In,
           void* __restrict__ OutV,
           const float* __restrict__ bnp,
           const float* __restrict__ res)
{
    constexpr int NT = KD / 64;
    constexpr int MT = MDIM / 128;
    __shared__ __align__(16) char lds[65536];

    const int t    = threadIdx.x;
    const int lane = t & 63;
    const int wave = t >> 6;
    const int wm = wave >> 1, wn = wave & 1;
    const int fr = lane & 15, fg = lane >> 4;

    // bijective XCD chunk swizzle, M-fastest (MT consecutive wg share a B panel)
    const int nwg = gridDim.x;
    int id = blockIdx.x;
    int q = nwg >> 3, r = nwg & 7;
    int xcd = id & 7, pos = id >> 3;
    int wg = (xcd < r ? xcd * (q + 1) : r * (q + 1) + (xcd - r) * q) + pos;
    const int m0 = (wg % MT) * 128;
    const int n0 = (wg / MT) * 128;

    // ---- staging: 32KB/K-tile = 8 gloads of 4KB ----
    const int pcu  = (((t & 7) ^ ((t >> 3) & 7)) << 3); // swizzled source col (ushorts)
    const int srow = t >> 3;                             // 0..31
    const unsigned short* pA[4];
    const unsigned short* pB[4];
    #pragma unroll
    for (int i = 0; i < 4; ++i) {
        pA[i] = W  + (size_t)(m0 + i * 32 + srow) * KD + pcu;
        pB[i] = In + (size_t)(n0 + i * 32 + srow) * KD + pcu;
    }
    auto stage = [&](int kt) {
        int kk = (kt < NT ? kt : NT - 1) * 64;
        char* base = lds + (kt & 1) * 32768 + t * 16;
        #pragma unroll
        for (int i = 0; i < 4; ++i) gload16(pA[i] + kk, base + i * 4096);
        #pragma unroll
        for (int i = 0; i < 4; ++i) gload16(pB[i] + kk, base + 16384 + i * 4096);
    };

    const int ko0 = (fg * 16) ^ ((fr & 7) << 4);
    const int ko1 = (64 + fg * 16) ^ ((fr & 7) << 4);
    const int arow = wm * 64 + fr;
    const int brow = wn * 64 + fr;

    f32x4 acc[4][4] = {};

    stage(0);

    for (int kt = 0; kt < NT; ++kt) {
        stage(kt + 1);
        asm volatile("s_waitcnt vmcnt(8)" ::: "memory"); // tile kt fully in LDS
        __builtin_amdgcn_s_barrier();
        __builtin_amdgcn_sched_barrier(0);               // reads stay below barrier

        const char* base = lds + (kt & 1) * 32768;
        bf16x8 afr[4][2], bfr[4][2];
        #pragma unroll
        for (int mf = 0; mf < 4; ++mf) {
            afr[mf][0] = ldlds(base + (arow + mf * 16) * 128 + ko0);
            afr[mf][1] = ldlds(base + (arow + mf * 16) * 128 + ko1);
        }
        #pragma unroll
        for (int nf = 0; nf < 4; ++nf) {
            bfr[nf][0] = ldlds(base + 16384 + (brow + nf * 16) * 128 + ko0);
            bfr[nf][1] = ldlds(base + 16384 + (brow + nf * 16) * 128 + ko1);
        }
        // compiler inserts counted lgkmcnt before each dependent MFMA -> overlap
        #pragma unroll
        for (int ks = 0; ks < 2; ++ks)
            #pragma unroll
            for (int mf = 0; mf < 4; ++mf)
                #pragma unroll
                for (int nf = 0; nf < 4; ++nf)
                    acc[mf][nf] = __builtin_amdgcn_mfma_f32_16x16x32_bf16(
                        afr[mf][ks], bfr[nf][ks], acc[mf][nf], 0, 0, 0);
        asm volatile("s_waitcnt lgkmcnt(0)" ::: "memory"); // ~free: MFMAs consumed all
        __builtin_amdgcn_sched_barrier(0);
        __builtin_amdgcn_s_barrier(); // all waves done reading buf kt
    }

    // drain DMA + sync before overlaying LDS for the epilogue
    asm volatile("s_waitcnt vmcnt(0)" ::: "memory");
    __builtin_amdgcn_s_barrier();

    if (EPI < 2) {
        // [128 col][136 o-slot] u16 staging (row stride 272B -> 16B aligned)
        unsigned short* eL = (unsigned short*)lds;
        unsigned short* Out = (unsigned short*)OutV;
        #pragma unroll
        for (int mf = 0; mf < 4; ++mf) {
            const int o_l = wm * 64 + mf * 16 + fg * 4;
            f32x4 inv = *(const f32x4*)(bnp + m0 + o_l);
            f32x4 sh  = *(const f32x4*)(bnp + MDIM + m0 + o_l);
            #pragma unroll
            for (int nf = 0; nf < 4; ++nf) {
                const int col_l = wn * 64 + nf * 16 + fr;
                u16x4 pk;
                #pragma unroll
                for (int rr = 0; rr < 4; ++rr) {
                    float v = acc[mf][nf][rr] * inv[rr] + sh[rr];
                    if (EPI == 1) v = gelu_fast(v);
                    pk[rr] = f2bf(v);
                }
                *(u16x4*)(eL + col_l * 136 + o_l) = pk;
            }
        }
        __builtin_amdgcn_s_barrier();
        #pragma unroll
        for (int i = 0; i < 8; ++i) {
            const int col_l = (t >> 4) + i * 16;
            const int o8 = (t & 15) * 8;
            u16x8 v = *(const u16x8*)(eL + col_l * 136 + o8);
            *(u16x8*)(Out + (size_t)(n0 + col_l) * 768 + m0 + o8) = v;
        }
    } else {
        // two halves of [64 o][132 col] fp32 staging; coalesced dword IO
        float* eL = (float*)lds;
        float* Out = (float*)OutV;
        #pragma unroll
        for (int h = 0; h < 2; ++h) {
            if (wm == h) {
                #pragma unroll
                for (int mf = 0; mf < 4; ++mf) {
                    const int o_l = mf * 16 + fg * 4;
                    f32x4 inv = *(const f32x4*)(bnp + m0 + h * 64 + o_l);
                    f32x4 sh  = *(const f32x4*)(bnp + MDIM + m0 + h * 64 + o_l);
                    #pragma unroll
                    for (int nf = 0; nf < 4; ++nf) {
                        const int col_l = wn * 64 + nf * 16 + fr;
                        #pragma unroll
                        for (int rr = 0; rr < 4; ++rr)
                            eL[(o_l + rr) * 132 + col_l] =
                                acc[mf][nf][rr] * inv[rr] + sh[rr];
                    }
                }
            }
            __builtin_amdgcn_s_barrier();
            #pragma unroll
            for (int i = 0; i < 32; ++i) {
                const int idx = i * 256 + t;
                const int o_i = idx >> 7, col = idx & 127;
                const int col_g = n0 + col;
                const int b = col_g / P_;
                const int p = col_g - b * P_;
                const size_t adr = (size_t)b * 384 * P_ + (size_t)(m0 + h * 64 + o_i) * P_ + p;
                Out[adr] = eL[o_i * 132 + col] + res[adr];
            }
            __builtin_amdgcn_s_barrier();
        }
    }
}

// ---------------- mrconv pass 1: per-(b, w|h) parity mins ----------------
#define MINSEG (16 * 2 * 56 * 384)
__global__ __launch_bounds__(384)
void mr_min(const unsigned short* __restrict__ y, float* __restrict__ mins)
{
    const int c = threadIdx.x;
    const int q = blockIdx.x;
    const int b = blockIdx.y;
    const unsigned short* yb = y + (size_t)b * P_ * 768;
    float m1e = 3.4e38f, m2e = 3.4e38f, m1o = 3.4e38f, m2o = 3.4e38f;
    if (q < 56) {
        int w = q;
        for (int h = 0; h < 56; h += 2) {
            float v0 = bf2f(yb[(size_t)(h * 56 + w) * 768 + c]);
            float v1 = bf2f(yb[(size_t)((h + 1) * 56 + w) * 768 + c]);
            if (v0 < m1e) { m2e = m1e; m1e = v0; } else if (v0 < m2e) m2e = v0;
            if (v1 < m1o) { m2o = m1o; m1o = v1; } else if (v1 < m2o) m2o = v1;
        }
        float* cm1 = mins;
        float* cm2 = mins + MINSEG;
        cm1[((b * 2 + 0) * 56 + w) * 384 + c] = m1e;
        cm1[((b * 2 + 1) * 56 + w) * 384 + c] = m1o;
        cm2[((b * 2 + 0) * 56 + w) * 384 + c] = m2e;
        cm2[((b * 2 + 1) * 56 + w) * 384 + c] = m2o;
    } else {
        int h = q - 56;
        for (int w = 0; w < 56; w += 2) {
            float v0 = bf2f(yb[(size_t)(h * 56 + w) * 768 + c]);
            float v1 = bf2f(yb[(size_t)(h * 56 + w + 1) * 768 + c]);
            if (v0 < m1e) { m2e = m1e; m1e = v0; } else if (v0 < m2e) m2e = v0;
            if (v1 < m1o) { m2o = m1o; m1o = v1; } else if (v1 < m2o) m2o = v1;
        }
        float* rm1 = mins + 2 * MINSEG;
        float* rm2 = mins + 3 * MINSEG;
        rm1[((b * 2 + 0) * 56 + h) * 384 + c] = m1e;
        rm1[((b * 2 + 1) * 56 + h) * 384 + c] = m1o;
        rm2[((b * 2 + 0) * 56 + h) * 384 + c] = m2e;
        rm2[((b * 2 + 1) * 56 + h) * 384 + c] = m2o;
    }
}

// ---------------- mrconv pass 2: combine -> y[:, 384:768] ----------------
__global__ __launch_bounds__(384)
void mr_comb(unsigned short* __restrict__ y, const float* __restrict__ mins)
{
    const int c = threadIdx.x;
    const int h = blockIdx.x;
    const int b = blockIdx.y;
    unsigned short* yb = y + (size_t)b * P_ * 768;
    const float* cm1 = mins;
    const float* cm2 = mins + MINSEG;
    const float* rm1 = mins + 2 * MINSEG;
    const float* rm2 = mins + 3 * MINSEG;
    const int parh = h & 1;
    float r1e = rm1[((b * 2 + 0) * 56 + h) * 384 + c];
    float r2e = rm2[((b * 2 + 0) * 56 + h) * 384 + c];
    float r1o = rm1[((b * 2 + 1) * 56 + h) * 384 + c];
    float r2o = rm2[((b * 2 + 1) * 56 + h) * 384 + c];
    #pragma unroll 2
    for (int w = 0; w < 56; ++w) {
        float v  = bf2f(yb[(size_t)(h * 56 + w) * 768 + c]);
        float c1 = cm1[((b * 2 + parh) * 56 + w) * 384 + c];
        float c2 = cm2[((b * 2 + parh) * 56 + w) * 384 + c];
        float mh = v > c1 ? c1 : c2;
        float rw1 = (w & 1) ? r1o : r1e;
        float rw2 = (w & 1) ? r2o : r2e;
        float mw = v > rw1 ? rw1 : rw2;
        float xj = fmaxf(0.0f, v - fminf(mh, mw));
        yb[(size_t)(h * 56 + w) * 768 + 384 + c] = f2bf(xj);
    }
}

extern "C" void kernel_launch(void* const* d_in, const int* in_sizes, int n_in,
                              void* d_out, int out_size, void* d_ws, size_t ws_size,
                              hipStream_t stream)
{
    const float* x      = (const float*)d_in[0];
    const float* fc1_w  = (const float*)d_in[1];
    const float* fc1_b  = (const float*)d_in[2];
    const float* fc1_g  = (const float*)d_in[3];
    const float* fc1_be = (const float*)d_in[4];
    const float* fc1_m  = (const float*)d_in[5];
    const float* fc1_v  = (const float*)d_in[6];
    const float* gc_w   = (const float*)d_in[7];
    const float* gc_b   = (const float*)d_in[8];
    const float* gc_g   = (const float*)d_in[9];
    const float* gc_be  = (const float*)d_in[10];
    const float* gc_m   = (const float*)d_in[11];
    const float* gc_v   = (const float*)d_in[12];
    const float* fc2_w  = (const float*)d_in[13];
    const float* fc2_b  = (const float*)d_in[14];
    const float* fc2_g  = (const float*)d_in[15];
    const float* fc2_be = (const float*)d_in[16];
    const float* fc2_m  = (const float*)d_in[17];
    const float* fc2_v  = (const float*)d_in[18];

    char* ws = (char*)d_ws;
    unsigned short* y   = (unsigned short*)ws;                       // [NTOT][768] bf16
    unsigned short* g   = y + (size_t)NTOT * 768;                    // [NTOT][768] bf16
    unsigned short* xT  = g + (size_t)NTOT * 768;                    // [NTOT][384] bf16
    unsigned short* wb1 = xT + (size_t)NTOT * 384;                   // [384][384]
    unsigned short* wb2 = wb1 + 384 * 384;                           // [768][768]
    unsigned short* wb3 = wb2 + 768 * 768;                           // [384][768]
    float* bn1 = (float*)(wb3 + 384 * 768);                          // [2][384]
    float* bn2 = bn1 + 2 * 384;                                      // [2][768]
    float* bn3 = bn2 + 2 * 768;                                      // [2][384]
    float* mins = bn3 + 2 * 384;                                     // 4 * MINSEG

    // weights->bf16 (1008 blocks) + BN fold (6 blocks)
    prep_wb<<<1014, 256, 0, stream>>>(fc1_w, gc_w, fc2_w, wb1, wb2, wb3,
                                      fc1_b, fc1_g, fc1_be, fc1_m, fc1_v,
                                      gc_b, gc_g, gc_be, gc_m, gc_v,
                                      fc2_b, fc2_g, fc2_be, fc2_m, fc2_v,
                                      bn1, bn2, bn3);
    prep_xT<<<dim3(6, 49, 16), 256, 0, stream>>>(x, xT);

    // y[:, 0:384] = bn(fc1 @ x)
    gemmF<384, 384, 0><<<dim3(3 * 392), 256, 0, stream>>>(wb1, xT, y, bn1, nullptr);
    // y[:, 384:768] = mrconv
    mr_min<<<dim3(112, 16), 384, 0, stream>>>(y, mins);
    mr_comb<<<dim3(56, 16), 384, 0, stream>>>(y, mins);
    // g = gelu(bn(gc @ y))
    gemmF<768, 768, 1><<<dim3(6 * 392), 256, 0, stream>>>(wb2, y, g, bn2, nullptr);
    // out = bn(fc2 @ g) + x
    gemmF<768, 384, 2><<<dim3(3 * 392), 256, 0, stream>>>(wb3, g, (void*)d_out, bn3, x);
}